// Round 3
// baseline (712.877 us; speedup 1.0000x reference)
//
#include <hip/hip_runtime.h>

#define N_PTS 131072
#define LOG2_T 19
#define TABLE_SIZE (1u << LOG2_T)
#define HASH_MASK (TABLE_SIZE - 1u)

typedef float f32x4 __attribute__((ext_vector_type(4)));

// thread = (point, encoding, level-half). 8 groups g = (enc<<1)|half, pinned
// to XCD g (block b -> XCD b%8 round-robin) so each XCD streams through its
// 8 level-tables in temporal sync: active working set ~ one 4MB table = L2.
// Each thread: 64 independent gathers (8 levels x 8 corners) -> deep MLP,
// then ONE full 64B output line (16 floats) via nontemporal stores.
__global__ __launch_bounds__(256, 4) void earth4d_kernel(
    const float* __restrict__ xyzt,
    const float* __restrict__ tab_xyz,
    const float* __restrict__ tab_xyt,
    const float* __restrict__ tab_yzt,
    const float* __restrict__ tab_xzt,
    float* __restrict__ out)
{
    unsigned b     = blockIdx.x;            // 0..4095
    unsigned g     = b & 7u;                // group == XCD, 0..7
    unsigned chunk = b >> 3;                // 0..511
    unsigned e     = g >> 1;                // encoding 0..3
    unsigned h     = g & 1u;                // level half 0..1
    unsigned n     = (chunk << 8) | threadIdx.x;  // point 0..131071

    float4 p = reinterpret_cast<const float4*>(xyzt)[n];

    float c0, c1, c2;
    const float* tab;
    switch (e) {
      case 0:  c0 = p.x; c1 = p.y; c2 = p.z; tab = tab_xyz; break;  // xyz
      case 1:  c0 = p.x; c1 = p.y; c2 = p.w; tab = tab_xyt; break;  // xyt
      case 2:  c0 = p.y; c1 = p.z; c2 = p.w; tab = tab_yzt; break;  // yzt
      default: c0 = p.x; c1 = p.z; c2 = p.w; tab = tab_xzt; break;  // xzt
    }

    float o[16];

    #pragma unroll
    for (int l = 0; l < 8; ++l) {
        unsigned L = h * 8u + (unsigned)l;
        const float2* tl = reinterpret_cast<const float2*>(tab) + (size_t)L * TABLE_SIZE;

        unsigned resu = 32u << L;           // 32 * 2^L, exact in fp32
        float res = (float)resu;
        float p0 = c0 * res, p1 = c1 * res, p2 = c2 * res;  // exact (res = 2^k)
        float f0 = floorf(p0), f1 = floorf(p1), f2 = floorf(p2);
        float w0 = p0 - f0, w1 = p1 - f1, w2 = p2 - f2;
        int b0 = (int)f0, b1 = (int)f1, b2 = (int)f2;

        unsigned idx[8];
        if (L < 2u) {
            // dense: (res+1)^3 <= 2^19 only for res in {32, 64}
            int s = (int)resu + 1;
            #pragma unroll
            for (int c = 0; c < 8; ++c) {
                int i0 = b0 + ((c >> 2) & 1);
                int i1 = b1 + ((c >> 1) & 1);
                int i2 = b2 + (c & 1);
                idx[c] = (unsigned)(i0 + i1 * s + i2 * s * s);
            }
        } else {
            #pragma unroll
            for (int c = 0; c < 8; ++c) {
                unsigned i0 = (unsigned)(b0 + ((c >> 2) & 1));
                unsigned i1 = (unsigned)(b1 + ((c >> 1) & 1));
                unsigned i2 = (unsigned)(b2 + (c & 1));
                idx[c] = (i0 * 1u ^ i1 * 2654435761u ^ i2 * 805459861u) & HASH_MASK;
            }
        }

        float a0 = 0.f, a1 = 0.f;
        #pragma unroll
        for (int c = 0; c < 8; ++c) {
            float2 f = tl[idx[c]];
            float wt = ((c & 4) ? w0 : 1.f - w0)
                     * ((c & 2) ? w1 : 1.f - w1)
                     * ((c & 1) ? w2 : 1.f - w2);
            a0 = fmaf(f.x, wt, a0);
            a1 = fmaf(f.y, wt, a1);
        }
        o[2 * l]     = a0;   // static indices (l is unroll-constant)
        o[2 * l + 1] = a1;
    }

    // One full 64B line per thread: out[n, e*32 + h*16 .. +16).
    // Nontemporal: output is write-once, keep it from evicting tables in L2.
    float* dst = out + (size_t)n * 128u + e * 32u + h * 16u;
    #pragma unroll
    for (int k = 0; k < 4; ++k) {
        f32x4 v = { o[4*k], o[4*k+1], o[4*k+2], o[4*k+3] };
        __builtin_nontemporal_store(v, reinterpret_cast<f32x4*>(dst) + k);
    }
}

extern "C" void kernel_launch(void* const* d_in, const int* in_sizes, int n_in,
                              void* d_out, int out_size, void* d_ws, size_t ws_size,
                              hipStream_t stream) {
    const float* xyzt    = (const float*)d_in[0];
    const float* tab_xyz = (const float*)d_in[1];
    const float* tab_xyt = (const float*)d_in[2];
    const float* tab_yzt = (const float*)d_in[3];
    const float* tab_xzt = (const float*)d_in[4];
    float* out = (float*)d_out;

    // 8 groups (enc x half) * 512 point-chunks = 4096 blocks of 256 threads
    dim3 grid(4096u), block(256u);
    earth4d_kernel<<<grid, block, 0, stream>>>(xyzt, tab_xyz, tab_xyt, tab_yzt, tab_xzt, out);
}

// Round 4
// 428.915 us; speedup vs baseline: 1.6620x; 1.6620x over previous
//
#include <hip/hip_runtime.h>

#define N_PTS 131072
#define LOG2_T 19
#define TABLE_SIZE (1u << LOG2_T)
#define HASH_MASK (TABLE_SIZE - 1u)

typedef float f32x2 __attribute__((ext_vector_type(2)));

// R0 locality structure (block = one (enc,level) combo; XCD-pinned so each
// XCD works one 4MB table at a time) + 4 points per thread for 32 gathers
// in flight per wave (vs 8 in R0). Batched: all idx -> all loads -> all FMA.
__global__ __launch_bounds__(256, 4) void earth4d_kernel(
    const float* __restrict__ xyzt,
    const float* __restrict__ tab_xyz,
    const float* __restrict__ tab_xyt,
    const float* __restrict__ tab_yzt,
    const float* __restrict__ tab_xzt,
    float* __restrict__ out)
{
    unsigned b     = blockIdx.x;               // 0..8191
    unsigned xcd   = b & 7u;
    unsigned i     = b >> 3;                   // 0..1023
    unsigned combo = ((i >> 7) << 3) | xcd;    // 0..63, combo%8==xcd
    unsigned chunk = i & 127u;                 // 0..127
    unsigned e     = combo >> 4;               // encoding 0..3
    unsigned l     = combo & 15u;              // level 0..15

    const float* tab;
    switch (e) {
      case 0:  tab = tab_xyz; break;
      case 1:  tab = tab_xyt; break;
      case 2:  tab = tab_yzt; break;
      default: tab = tab_xzt; break;
    }
    const f32x2* tl = reinterpret_cast<const f32x2*>(tab) + (size_t)l * TABLE_SIZE;

    unsigned resu = 32u << l;                  // 32 * 2^l, exact
    float res = (float)resu;

    unsigned nbase = (chunk << 10) | threadIdx.x;   // + k*256, k=0..3

    float w0[4], w1[4], w2[4];
    unsigned idx[4][8];

    #pragma unroll
    for (int k = 0; k < 4; ++k) {
        unsigned n = nbase + (unsigned)k * 256u;
        float4 p = reinterpret_cast<const float4*>(xyzt)[n];
        float c0, c1, c2;
        switch (e) {
          case 0:  c0 = p.x; c1 = p.y; c2 = p.z; break;  // xyz
          case 1:  c0 = p.x; c1 = p.y; c2 = p.w; break;  // xyt
          case 2:  c0 = p.y; c1 = p.z; c2 = p.w; break;  // yzt
          default: c0 = p.x; c1 = p.z; c2 = p.w; break;  // xzt
        }
        float p0 = c0 * res, p1 = c1 * res, p2 = c2 * res;   // exact (res=2^k)
        float f0 = floorf(p0), f1 = floorf(p1), f2 = floorf(p2);
        w0[k] = p0 - f0; w1[k] = p1 - f1; w2[k] = p2 - f2;
        int b0 = (int)f0, b1 = (int)f1, b2 = (int)f2;

        if (l < 2u) {
            // dense: (res+1)^3 <= 2^19 only for res in {32, 64}
            int s = (int)resu + 1;
            #pragma unroll
            for (int c = 0; c < 8; ++c) {
                int i0 = b0 + ((c >> 2) & 1);
                int i1 = b1 + ((c >> 1) & 1);
                int i2 = b2 + (c & 1);
                idx[k][c] = (unsigned)(i0 + i1 * s + i2 * s * s);
            }
        } else {
            #pragma unroll
            for (int c = 0; c < 8; ++c) {
                unsigned i0 = (unsigned)(b0 + ((c >> 2) & 1));
                unsigned i1 = (unsigned)(b1 + ((c >> 1) & 1));
                unsigned i2 = (unsigned)(b2 + (c & 1));
                idx[k][c] = (i0 * 1u ^ i1 * 2654435761u ^ i2 * 805459861u) & HASH_MASK;
            }
        }
    }

    // Batch-issue all 32 gathers (independent -> 32 outstanding per lane).
    f32x2 v[4][8];
    #pragma unroll
    for (int k = 0; k < 4; ++k)
        #pragma unroll
        for (int c = 0; c < 8; ++c)
            v[k][c] = tl[idx[k][c]];

    #pragma unroll
    for (int k = 0; k < 4; ++k) {
        float a0 = 0.f, a1 = 0.f;
        #pragma unroll
        for (int c = 0; c < 8; ++c) {
            float wt = ((c & 4) ? w0[k] : 1.f - w0[k])
                     * ((c & 2) ? w1[k] : 1.f - w1[k])
                     * ((c & 1) ? w2[k] : 1.f - w2[k]);
            a0 = fmaf(v[k][c].x, wt, a0);
            a1 = fmaf(v[k][c].y, wt, a1);
        }
        unsigned n = nbase + (unsigned)k * 256u;
        f32x2 r = { a0, a1 };
        // write-once output: nontemporal, keep tables resident in L2
        __builtin_nontemporal_store(
            r, reinterpret_cast<f32x2*>(out + (size_t)n * 128u + combo * 2u));
    }
}

extern "C" void kernel_launch(void* const* d_in, const int* in_sizes, int n_in,
                              void* d_out, int out_size, void* d_ws, size_t ws_size,
                              hipStream_t stream) {
    const float* xyzt    = (const float*)d_in[0];
    const float* tab_xyz = (const float*)d_in[1];
    const float* tab_xyt = (const float*)d_in[2];
    const float* tab_yzt = (const float*)d_in[3];
    const float* tab_xzt = (const float*)d_in[4];
    float* out = (float*)d_out;

    // 64 combos * 128 point-chunks (1024 pts each) = 8192 blocks of 256 threads
    dim3 grid(8192u), block(256u);
    earth4d_kernel<<<grid, block, 0, stream>>>(xyzt, tab_xyz, tab_xyt, tab_yzt, tab_xzt, out);
}

// Round 5
// 341.620 us; speedup vs baseline: 2.0868x; 1.2555x over previous
//
#include <hip/hip_runtime.h>

#define N_PTS 131072
#define LOG2_T 19
#define TABLE_SIZE (1u << LOG2_T)
#define HASH_MASK (TABLE_SIZE - 1u)

typedef float f32x2 __attribute__((ext_vector_type(2)));
typedef float f32x4 __attribute__((ext_vector_type(4)));

// Kernel 1: gather. R4 structure (block = one (enc,level) combo, XCD-pinned,
// 4 points/thread batched). Stores go combo-major to ws: fully coalesced
// full-line NT stores -> no partial-line RMW at HBM, no L2/L3 pollution,
// tables stay L3-resident across graph replays.
template <bool USE_WS>
__global__ __launch_bounds__(256, 4) void earth4d_gather(
    const float* __restrict__ xyzt,
    const float* __restrict__ tab_xyz,
    const float* __restrict__ tab_xyt,
    const float* __restrict__ tab_yzt,
    const float* __restrict__ tab_xzt,
    float* __restrict__ out,
    f32x2* __restrict__ ws)
{
    unsigned b     = blockIdx.x;               // 0..8191
    unsigned xcd   = b & 7u;
    unsigned i     = b >> 3;                   // 0..1023
    unsigned combo = ((i >> 7) << 3) | xcd;    // 0..63, combo%8==xcd
    unsigned chunk = i & 127u;                 // 0..127
    unsigned e     = combo >> 4;               // encoding 0..3
    unsigned l     = combo & 15u;              // level 0..15

    const float* tab;
    switch (e) {
      case 0:  tab = tab_xyz; break;
      case 1:  tab = tab_xyt; break;
      case 2:  tab = tab_yzt; break;
      default: tab = tab_xzt; break;
    }
    const f32x2* tl = reinterpret_cast<const f32x2*>(tab) + (size_t)l * TABLE_SIZE;

    unsigned resu = 32u << l;                  // 32 * 2^l, exact
    float res = (float)resu;

    unsigned nbase = (chunk << 10) | threadIdx.x;   // + k*256, k=0..3

    float w0[4], w1[4], w2[4];
    unsigned idx[4][8];

    #pragma unroll
    for (int k = 0; k < 4; ++k) {
        unsigned n = nbase + (unsigned)k * 256u;
        float4 p = reinterpret_cast<const float4*>(xyzt)[n];
        float c0, c1, c2;
        switch (e) {
          case 0:  c0 = p.x; c1 = p.y; c2 = p.z; break;  // xyz
          case 1:  c0 = p.x; c1 = p.y; c2 = p.w; break;  // xyt
          case 2:  c0 = p.y; c1 = p.z; c2 = p.w; break;  // yzt
          default: c0 = p.x; c1 = p.z; c2 = p.w; break;  // xzt
        }
        float p0 = c0 * res, p1 = c1 * res, p2 = c2 * res;   // exact (res=2^k)
        float f0 = floorf(p0), f1 = floorf(p1), f2 = floorf(p2);
        w0[k] = p0 - f0; w1[k] = p1 - f1; w2[k] = p2 - f2;
        int b0 = (int)f0, b1 = (int)f1, b2 = (int)f2;

        if (l < 2u) {
            // dense: (res+1)^3 <= 2^19 only for res in {32, 64}
            int s = (int)resu + 1;
            #pragma unroll
            for (int c = 0; c < 8; ++c) {
                int i0 = b0 + ((c >> 2) & 1);
                int i1 = b1 + ((c >> 1) & 1);
                int i2 = b2 + (c & 1);
                idx[k][c] = (unsigned)(i0 + i1 * s + i2 * s * s);
            }
        } else {
            #pragma unroll
            for (int c = 0; c < 8; ++c) {
                unsigned i0 = (unsigned)(b0 + ((c >> 2) & 1));
                unsigned i1 = (unsigned)(b1 + ((c >> 1) & 1));
                unsigned i2 = (unsigned)(b2 + (c & 1));
                idx[k][c] = (i0 * 1u ^ i1 * 2654435761u ^ i2 * 805459861u) & HASH_MASK;
            }
        }
    }

    // Batch-issue all 32 gathers (independent).
    f32x2 v[4][8];
    #pragma unroll
    for (int k = 0; k < 4; ++k)
        #pragma unroll
        for (int c = 0; c < 8; ++c)
            v[k][c] = tl[idx[k][c]];

    #pragma unroll
    for (int k = 0; k < 4; ++k) {
        float a0 = 0.f, a1 = 0.f;
        #pragma unroll
        for (int c = 0; c < 8; ++c) {
            float wt = ((c & 4) ? w0[k] : 1.f - w0[k])
                     * ((c & 2) ? w1[k] : 1.f - w1[k])
                     * ((c & 1) ? w2[k] : 1.f - w2[k]);
            a0 = fmaf(v[k][c].x, wt, a0);
            a1 = fmaf(v[k][c].y, wt, a1);
        }
        unsigned n = nbase + (unsigned)k * 256u;
        f32x2 r = { a0, a1 };
        if (USE_WS) {
            // combo-major: consecutive lanes -> consecutive 8B, full-line NT
            __builtin_nontemporal_store(r, ws + (size_t)combo * N_PTS + n);
        } else {
            __builtin_nontemporal_store(
                r, reinterpret_cast<f32x2*>(out + (size_t)n * 128u + combo * 2u));
        }
    }
}

// Kernel 2: transpose ws[combo][n] -> out[n][128]. 64-point tiles via LDS.
// NT read (ws used once), NT full-line writes (don't evict tables from L3).
__global__ __launch_bounds__(256) void earth4d_transpose(
    const f32x2* __restrict__ ws, float* __restrict__ out)
{
    __shared__ f32x2 lds[64][65];   // pad: stride 65*8B -> 2-way bank alias (free)
    unsigned n0 = blockIdx.x * 64u;
    unsigned t = threadIdx.x;

    #pragma unroll
    for (int it = 0; it < 16; ++it) {
        unsigned i = (unsigned)it * 256u + t;     // 0..4095
        unsigned c = i >> 6;                      // combo 0..63
        unsigned p = i & 63u;                     // point-in-tile
        lds[p][c] = __builtin_nontemporal_load(ws + (size_t)c * N_PTS + n0 + p);
    }
    __syncthreads();

    #pragma unroll
    for (int it = 0; it < 8; ++it) {
        unsigned i = (unsigned)it * 256u + t;     // 0..2047
        unsigned p = i >> 5;                      // point-in-tile 0..63
        unsigned q = i & 31u;                     // float4 index 0..31
        f32x2 a = lds[p][2u * q];
        f32x2 b = lds[p][2u * q + 1u];
        f32x4 v = { a.x, a.y, b.x, b.y };
        __builtin_nontemporal_store(
            v, reinterpret_cast<f32x4*>(out + (size_t)(n0 + p) * 128u) + q);
    }
}

extern "C" void kernel_launch(void* const* d_in, const int* in_sizes, int n_in,
                              void* d_out, int out_size, void* d_ws, size_t ws_size,
                              hipStream_t stream) {
    const float* xyzt    = (const float*)d_in[0];
    const float* tab_xyz = (const float*)d_in[1];
    const float* tab_xyt = (const float*)d_in[2];
    const float* tab_yzt = (const float*)d_in[3];
    const float* tab_xzt = (const float*)d_in[4];
    float* out = (float*)d_out;

    const size_t ws_needed = (size_t)64 * N_PTS * sizeof(f32x2);  // 64 MB
    dim3 grid1(8192u), block(256u);

    if (ws_size >= ws_needed && d_ws) {
        f32x2* ws = (f32x2*)d_ws;
        earth4d_gather<true><<<grid1, block, 0, stream>>>(
            xyzt, tab_xyz, tab_xyt, tab_yzt, tab_xzt, out, ws);
        earth4d_transpose<<<dim3(N_PTS / 64u), block, 0, stream>>>(ws, out);
    } else {
        earth4d_gather<false><<<grid1, block, 0, stream>>>(
            xyzt, tab_xyz, tab_xyt, tab_yzt, tab_xzt, out, (f32x2*)nullptr);
    }
}